// Round 11
// baseline (220.354 us; speedup 1.0000x reference)
//
#include <hip/hip_runtime.h>
#include <hip/hip_bf16.h>
#include <math.h>

#define NS 4096      // samples
#define NC 512       // clusters
#define ND 64        // feature dim
#define NK 10        // classes
#define NPAIR 2080   // upper-triangle pairs (e<=d) of 64x64
#define KP 2176      // 2080 + 64 (linear) + 1 (const) + 31 zero-pad; 68*32
#define BOFF 2080
#define KOFF 2144
#define KSPLIT 4
#define KT_PER (KP / 32 / KSPLIT)   // 17 k-chunks per split block

typedef __attribute__((ext_vector_type(8))) short short8;
typedef __attribute__((ext_vector_type(4))) float floatx4;

__device__ inline unsigned short f2b(float x) {
    __hip_bfloat16 h = __float2bfloat16(x);           // RNE
    return __builtin_bit_cast(unsigned short, h);
}
__device__ inline float b2f(unsigned short u) {
    __hip_bfloat16 h = __builtin_bit_cast(__hip_bfloat16, u);
    return __bfloat162float(h);
}

// ---------------- pair-index tables ----------------
__global__ void table_kernel(int* __restrict__ eop, int* __restrict__ dop) {
    const int e = threadIdx.x;                        // 64 threads
    int off = e * 64 - (e * (e - 1)) / 2;             // row e starts here
    for (int d = e; d < 64; ++d) { eop[off + d - e] = e; dop[off + d - e] = d; }
}

#define FOR16(M) M(0) M(1) M(2) M(3) M(4) M(5) M(6) M(7) \
                 M(8) M(9) M(10) M(11) M(12) M(13) M(14) M(15)

// ---------------- fused prep (Sigma^-1 + beta pack) and qbuild --------------
// R10 re-diagnosis: prep's arrays WERE in registers; the 66-71us came from the
// scheduler serializing the 16 colk ds_read_b128 (pressure heuristic). Fix:
// inline-asm blob issuing all 16 reads back-to-back with one lgkmcnt(0) and
// 16 early-clobber float4 outputs -> grouped issue is pinned at ISA level.
__global__ __launch_bounds__(256, 1) void prep_qbuild_kernel(
    const float* __restrict__ S, const float* __restrict__ n,
    const float* __restrict__ mu, const int* __restrict__ clab,
    const float* __restrict__ data, const int* __restrict__ eop,
    const int* __restrict__ dop, unsigned short* __restrict__ Bph,
    unsigned short* __restrict__ Bpl, unsigned short* __restrict__ Qh,
    unsigned short* __restrict__ Ql, float* __restrict__ d2,
    float* __restrict__ labf)
{
    __shared__ float smem[ND * (ND + 1) + 2 * ND];
    float* __restrict__ AcolS = smem;                 // [64][65] Sinv mirror
    float* __restrict__ colk  = smem + ND * (ND + 1); // column-k broadcast / z
    float* __restrict__ cbuf  = colk + ND;            // bvec staging

    if (blockIdx.x >= NC) {
        // ---------------- qbuild role ----------------
        const int s = blockIdx.x - NC;
        float* __restrict__ z = colk;
        if (threadIdx.x < ND) z[threadIdx.x] = data[(size_t)s * ND + threadIdx.x];
        *(float2*)&d2[(size_t)s * NC + threadIdx.x * 2] = make_float2(0.f, 0.f);
        __syncthreads();
        for (int p = threadIdx.x; p < KP; p += 256) {
            float val;
            if (p < NPAIR)      val = z[eop[p]] * z[dop[p]];
            else if (p < KOFF)  val = z[p - BOFF];
            else if (p == KOFF) val = 1.0f;
            else                val = 0.f;
            const unsigned short h = f2b(val);
            const unsigned short l = f2b(val - b2f(h));
            Qh[(size_t)s * KP + p] = h;
            Ql[(size_t)s * KP + p] = l;
        }
        return;
    }

    // ---------------- prep role: wave 0 only (no __syncthreads below) -------
    if (threadIdx.x >= 64) return;
    const int c = blockIdx.x;
    const int j = threadIdx.x;                        // column owned by this lane
    const unsigned colk_addr = (unsigned)(unsigned long long)(void*)colk;  // LDS byte offset

    const float inv_nc = 1.0f / n[c];
    const float* __restrict__ Sc = S + (size_t)c * ND * ND + j;

#define DECL(t) float4 A##t;
    FOR16(DECL)
#undef DECL

#define LOADT(t) {                                                   \
    const float x0 = Sc[(4*t+0)*ND] * inv_nc;                        \
    const float x1 = Sc[(4*t+1)*ND] * inv_nc;                        \
    const float x2 = Sc[(4*t+2)*ND] * inv_nc;                        \
    const float x3 = Sc[(4*t+3)*ND] * inv_nc;                        \
    A##t.x = (4*t+0 == j) ? x0 + 1e-6f : x0;                         \
    A##t.y = (4*t+1 == j) ? x1 + 1e-6f : x1;                         \
    A##t.z = (4*t+2 == j) ? x2 + 1e-6f : x2;                         \
    A##t.w = (4*t+3 == j) ? x3 + 1e-6f : x3; }
    FOR16(LOADT)
#undef LOADT

    for (int k = 0; k < ND; ++k) {
        if (j == k) {                                 // publish column k (pre-update)
#define PUB(t) *(float4*)&colk[4*t] = A##t;
            FOR16(PUB)
#undef PUB
        }
        __builtin_amdgcn_wave_barrier();
        const float rp = colk[j];                     // M[j][k] (lane-indexed LDS)
        const float p  = colk[k];                     // pivot (uniform LDS)
        // forced-ILP batch read of colk: 16 b128 issued back-to-back, 1 wait
        float4 k4_0,k4_1,k4_2,k4_3,k4_4,k4_5,k4_6,k4_7,
               k4_8,k4_9,k4_10,k4_11,k4_12,k4_13,k4_14,k4_15;
        asm volatile(
            "ds_read_b128 %0, %16 offset:0\n\t"
            "ds_read_b128 %1, %16 offset:16\n\t"
            "ds_read_b128 %2, %16 offset:32\n\t"
            "ds_read_b128 %3, %16 offset:48\n\t"
            "ds_read_b128 %4, %16 offset:64\n\t"
            "ds_read_b128 %5, %16 offset:80\n\t"
            "ds_read_b128 %6, %16 offset:96\n\t"
            "ds_read_b128 %7, %16 offset:112\n\t"
            "ds_read_b128 %8, %16 offset:128\n\t"
            "ds_read_b128 %9, %16 offset:144\n\t"
            "ds_read_b128 %10, %16 offset:160\n\t"
            "ds_read_b128 %11, %16 offset:176\n\t"
            "ds_read_b128 %12, %16 offset:192\n\t"
            "ds_read_b128 %13, %16 offset:208\n\t"
            "ds_read_b128 %14, %16 offset:224\n\t"
            "ds_read_b128 %15, %16 offset:240\n\t"
            "s_waitcnt lgkmcnt(0)"
            : "=&v"(k4_0), "=&v"(k4_1), "=&v"(k4_2), "=&v"(k4_3),
              "=&v"(k4_4), "=&v"(k4_5), "=&v"(k4_6), "=&v"(k4_7),
              "=&v"(k4_8), "=&v"(k4_9), "=&v"(k4_10), "=&v"(k4_11),
              "=&v"(k4_12), "=&v"(k4_13), "=&v"(k4_14), "=&v"(k4_15)
            : "v"(colk_addr)
            : "memory");
        const float ip   = 1.0f / p;
        const float rowk = (j == k) ? ip : ((j < k) ? -rp : rp) * ip;  // sign identity
        const float am   = (j == k) ? 0.0f : 1.0f;    // column-k pre-zero
#define UPD(t) {                                                     \
    const float rx = A##t.x * am - k4_##t.x * rowk;                  \
    const float ry = A##t.y * am - k4_##t.y * rowk;                  \
    const float rz = A##t.z * am - k4_##t.z * rowk;                  \
    const float rw = A##t.w * am - k4_##t.w * rowk;                  \
    A##t.x = (4*t+0 == k) ? rowk : rx;                               \
    A##t.y = (4*t+1 == k) ? rowk : ry;                               \
    A##t.z = (4*t+2 == k) ? rowk : rz;                               \
    A##t.w = (4*t+3 == k) ? rowk : rw; }
        FOR16(UPD)
#undef UPD
        __builtin_amdgcn_wave_barrier();
    }

    // mirror Sinv into LDS for the pack gather; fuse y = Sinv*mu
    float y = 0.f;
#define MIR(t) {                                                     \
    *(float4*)&AcolS[j * (ND + 1) + 4*t] = A##t;                     \
    y += A##t.x * mu[c*ND + 4*t]     + A##t.y * mu[c*ND + 4*t + 1]   \
       + A##t.z * mu[c*ND + 4*t + 2] + A##t.w * mu[c*ND + 4*t + 3]; }
    FOR16(MIR)
#undef MIR
    cbuf[j] = -2.0f * y;                              // bvec values
    float kk = mu[c * ND + j] * y;
    #pragma unroll
    for (int off = 32; off > 0; off >>= 1) kk += __shfl_down(kk, off);
    const float kks = __shfl(kk, 0);
    if (j == 0) {
        int lab = 0;
        for (int q = 0; q < NK; ++q) if (clab[c * NK + q] != 0) lab = q;
        labf[c] = (float)lab;
    }
    __builtin_amdgcn_wave_barrier();

    // fused pack: beta = [sym-folded Sinv, b, k, 0pad] as bf16 hi/lo
    unsigned short* __restrict__ ph = Bph + (size_t)c * KP;
    unsigned short* __restrict__ pl = Bpl + (size_t)c * KP;
    #pragma unroll
    for (int t = 0; t < KP / 64; ++t) {               // 34 iters, p = t*64+j
        const int p = t * 64 + j;
        float val;
        if (p < NPAIR) {
            const int e = eop[p], d = dop[p];
            val = (e == d) ? AcolS[e * (ND + 1) + e]
                           : (AcolS[d * (ND + 1) + e] + AcolS[e * (ND + 1) + d]);
        } else if (p < KOFF) val = cbuf[p - BOFF];
        else if (p == KOFF)  val = kks;
        else                 val = 0.f;
        const unsigned short h = f2b(val);
        const unsigned short l = f2b(val - b2f(h));
        ph[p] = h;
        pl[p] = l;
    }
}

// ---------------- d2[s][c] = Q · Beta^T via bf16x3 MFMA, split-K x4 ----------
// LDS-FREE gemm: at this size B (4.5 MB) is L2-resident and the A window is
// L1-resident (4 waves share it), so fragments are loaded DIRECTLY
// global->register (identical addresses to the old staging+frag-read
// composition -> bit-identical numerics). Per-wave 64x64 tile, ping-pong
// register double-buffer, ZERO barriers -> no vmcnt(0)-before-s_barrier drain.
// __launch_bounds__(256,2): raises scheduler pressure target so the prefetch
// set is not sunk (R10: default target sank prefetches, VGPR 76, MfmaUtil 16%).
__global__ __launch_bounds__(256, 2) void gemm_kernel(
    const unsigned short* __restrict__ Qh, const unsigned short* __restrict__ Ql,
    const unsigned short* __restrict__ Bph, const unsigned short* __restrict__ Bpl,
    float* __restrict__ d2)
{
    const int tid  = threadIdx.x;
    const int lane = tid & 63, w = tid >> 6;
    const int quad = lane >> 4, rlo = lane & 15;
    const int m0 = blockIdx.x * 64;      // sample tile (whole block)
    const int n0 = blockIdx.y * 256;     // cluster tile (w*64 per wave)
    const size_t kq = (size_t)blockIdx.z * KT_PER * 32 + quad * 8;

    size_t oA[4], oB[4];
    #pragma unroll
    for (int i = 0; i < 4; ++i) {
        oA[i] = (size_t)(m0 + i * 16 + rlo) * KP + kq;
        oB[i] = (size_t)(n0 + w * 64 + i * 16 + rlo) * KP + kq;
    }

    short8 ah[4], al[4], bh[4], bl[4], ahN[4], alN[4], bhN[4], blN[4];
    #pragma unroll
    for (int i = 0; i < 4; ++i) {
        ah[i] = *(const short8*)(Qh  + oA[i]);
        al[i] = *(const short8*)(Ql  + oA[i]);
        bh[i] = *(const short8*)(Bph + oB[i]);
        bl[i] = *(const short8*)(Bpl + oB[i]);
    }

    floatx4 acc[4][4] = {};

#define GSTEP(CAH, CAL, CBH, CBL, NAH, NAL, NBH, NBL, KT)                      \
    {                                                                          \
        if ((KT) + 1 < KT_PER) {                                               \
            const int ko = ((KT) + 1) * 32;                                    \
            _Pragma("unroll")                                                  \
            for (int i = 0; i < 4; ++i) {                                      \
                NAH[i] = *(const short8*)(Qh  + oA[i] + ko);                   \
                NAL[i] = *(const short8*)(Ql  + oA[i] + ko);                   \
                NBH[i] = *(const short8*)(Bph + oB[i] + ko);                   \
                NBL[i] = *(const short8*)(Bpl + oB[i] + ko);                   \
            }                                                                  \
        }                                                                      \
        _Pragma("unroll")                                                      \
        for (int i = 0; i < 4; ++i)                                            \
            _Pragma("unroll")                                                  \
            for (int j2 = 0; j2 < 4; ++j2) {                                   \
                acc[i][j2] = __builtin_amdgcn_mfma_f32_16x16x32_bf16(          \
                    CAL[i], CBH[j2], acc[i][j2], 0, 0, 0);                     \
                acc[i][j2] = __builtin_amdgcn_mfma_f32_16x16x32_bf16(          \
                    CAH[i], CBL[j2], acc[i][j2], 0, 0, 0);                     \
                acc[i][j2] = __builtin_amdgcn_mfma_f32_16x16x32_bf16(          \
                    CAH[i], CBH[j2], acc[i][j2], 0, 0, 0);                     \
            }                                                                  \
    }

    for (int kt = 0; kt < KT_PER; kt += 2) {           // ping-pong: no reg swaps
        GSTEP(ah, al, bh, bl, ahN, alN, bhN, blN, kt)
        if (kt + 1 < KT_PER)
            GSTEP(ahN, alN, bhN, blN, ah, al, bh, bl, kt + 1)
    }
#undef GSTEP

    // C layout (verified m89): col = lane&15, row = (lane>>4)*4 + reg
    #pragma unroll
    for (int i = 0; i < 4; ++i)
        #pragma unroll
        for (int j2 = 0; j2 < 4; ++j2) {
            const int m = m0 + i * 16 + quad * 4;
            const int nn = n0 + w * 64 + j2 * 16 + rlo;
            #pragma unroll
            for (int r = 0; r < 4; ++r)
                atomicAdd(&d2[(size_t)(m + r) * NC + nn], acc[i][j2][r]);
        }
}

// ---------------- scores / argmaxes: one wave per sample ----------------
__global__ __launch_bounds__(64) void score_kernel(
    const float* __restrict__ d2, const float* __restrict__ labf,
    float* __restrict__ out)
{
    const int s = blockIdx.x;
    const int l = threadIdx.x;

    float numer[NK];
    #pragma unroll
    for (int q = 0; q < NK; ++q) numer[q] = 0.f;
    float denom = 0.f, gmax = -1.f;
    int gidx = 0;

    #pragma unroll
    for (int i = 0; i < NC / 256; ++i) {         // float4 per lane, index-ascending
        const int c0 = i * 256 + l * 4;
        const float4 v = *(const float4*)&d2[(size_t)s * NC + c0];
        #pragma unroll
        for (int r = 0; r < 4; ++r) {
            const int c = c0 + r;
            const float G = __expf(-0.5f * ((const float*)&v)[r]);
            denom += G;
            const int lab = (int)labf[c];
            #pragma unroll
            for (int q = 0; q < NK; ++q) numer[q] += (q == lab) ? G : 0.f;
            if (G > gmax) { gmax = G; gidx = c; }   // strict > keeps first index
        }
    }

    // wave reduction (width 64); ties -> lowest cluster index (jnp first-max)
    #pragma unroll
    for (int off = 32; off > 0; off >>= 1) {
        const float og = __shfl_down(gmax, off);
        const int   oi = __shfl_down(gidx, off);
        if (og > gmax || (og == gmax && oi < gidx)) { gmax = og; gidx = oi; }
        denom += __shfl_down(denom, off);
        #pragma unroll
        for (int q = 0; q < NK; ++q) numer[q] += __shfl_down(numer[q], off);
    }

    if (l == 0) {
        const float inv = 1.0f / (denom + 1e-12f);
        float best = -1.f; int pk = 0;
        #pragma unroll
        for (int q = 0; q < NK; ++q) {
            const float sc = numer[q] * inv;
            out[(size_t)s * NK + q] = sc;
            if (sc > best) { best = sc; pk = q; }
        }
        out[(size_t)NS * NK + s]      = (float)pk;    // pred
        out[(size_t)NS * NK + NS + s] = (float)gidx;  // clusters
    }
}

extern "C" void kernel_launch(void* const* d_in, const int* in_sizes, int n_in,
                              void* d_out, int out_size, void* d_ws, size_t ws_size,
                              hipStream_t stream)
{
    const float* data = (const float*)d_in[0];
    const float* n    = (const float*)d_in[2];
    const float* mu   = (const float*)d_in[3];
    const float* S    = (const float*)d_in[4];
    const int*   clab = (const int*)d_in[5];

    char* w = (char*)d_ws;
    unsigned short* Qh  = (unsigned short*)(w);                 // 17,825,792 B
    unsigned short* Ql  = (unsigned short*)(w + 17825792);      // 17,825,792 B
    unsigned short* Bph = (unsigned short*)(w + 35651584);      //  2,228,224 B
    unsigned short* Bpl = (unsigned short*)(w + 37879808);      //  2,228,224 B
    float* d2   = (float*)(w + 40108032);                       //  8,388,608 B
    float* labf = (float*)(w + 48496640);                       //      2,048 B
    int*   eop  = (int*)  (w + 48498688);                       //      8,320 B
    int*   dop  = (int*)  (w + 48507008);                       //      8,320 B  (end 48,515,328)

    hipLaunchKernelGGL(table_kernel, dim3(1),   dim3(64),  0, stream, eop, dop);
    hipLaunchKernelGGL(prep_qbuild_kernel, dim3(NC + NS), dim3(256), 0, stream,
                       S, n, mu, clab, data, eop, dop, Bph, Bpl, Qh, Ql, d2, labf);
    hipLaunchKernelGGL(gemm_kernel,  dim3(NS / 64, NC / 256, KSPLIT), dim3(256), 0, stream,
                       Qh, Ql, Bph, Bpl, d2);
    hipLaunchKernelGGL(score_kernel, dim3(NS),  dim3(64),  0, stream,
                       d2, labf, (float*)d_out);
}

// Round 12
// 198.302 us; speedup vs baseline: 1.1112x; 1.1112x over previous
//
#include <hip/hip_runtime.h>
#include <hip/hip_bf16.h>
#include <math.h>

#define NS 4096      // samples
#define NC 512       // clusters
#define ND 64        // feature dim
#define NK 10        // classes
#define NPAIR 2080   // upper-triangle pairs (e<=d) of 64x64
#define KP 2176      // 2080 + 64 (linear) + 1 (const) + 31 zero-pad; 68*32
#define BOFF 2080
#define KOFF 2144
#define KSPLIT 4
#define KT_PER (KP / 32 / KSPLIT)   // 17 k-chunks per split block

typedef __attribute__((ext_vector_type(8))) short short8;
typedef __attribute__((ext_vector_type(4))) float floatx4;

__device__ inline unsigned short f2b(float x) {
    __hip_bfloat16 h = __float2bfloat16(x);           // RNE
    return __builtin_bit_cast(unsigned short, h);
}
__device__ inline float b2f(unsigned short u) {
    __hip_bfloat16 h = __builtin_bit_cast(__hip_bfloat16, u);
    return __bfloat162float(h);
}

// async global->LDS, 16B per lane (m97 lever). LDS dst is wave-uniform base +
// lane*16 -- both our lds pointers are computed exactly that way.
__device__ inline void gl16(const void* g, void* l) {
    __builtin_amdgcn_global_load_lds(
        (const __attribute__((address_space(1))) unsigned int*)g,
        (__attribute__((address_space(3))) unsigned int*)l, 16, 0, 0);
}

// ---------------- pair-index tables ----------------
__global__ void table_kernel(int* __restrict__ eop, int* __restrict__ dop) {
    const int e = threadIdx.x;                        // 64 threads
    int off = e * 64 - (e * (e - 1)) / 2;             // row e starts here
    for (int d = e; d < 64; ++d) { eop[off + d - e] = e; dop[off + d - e] = d; }
}

#define FOR16(M) M(0) M(1) M(2) M(3) M(4) M(5) M(6) M(7) \
                 M(8) M(9) M(10) M(11) M(12) M(13) M(14) M(15)

// ---------------- fused prep (Sigma^-1 + beta pack) and qbuild --------------
// (R11 version, kept byte-identical: named float4 regs + asm-batched colk
// reads. Passed R11; not the top dispatch.)
__global__ __launch_bounds__(256, 1) void prep_qbuild_kernel(
    const float* __restrict__ S, const float* __restrict__ n,
    const float* __restrict__ mu, const int* __restrict__ clab,
    const float* __restrict__ data, const int* __restrict__ eop,
    const int* __restrict__ dop, unsigned short* __restrict__ Bph,
    unsigned short* __restrict__ Bpl, unsigned short* __restrict__ Qh,
    unsigned short* __restrict__ Ql, float* __restrict__ d2,
    float* __restrict__ labf)
{
    __shared__ float smem[ND * (ND + 1) + 2 * ND];
    float* __restrict__ AcolS = smem;                 // [64][65] Sinv mirror
    float* __restrict__ colk  = smem + ND * (ND + 1); // column-k broadcast / z
    float* __restrict__ cbuf  = colk + ND;            // bvec staging

    if (blockIdx.x >= NC) {
        // ---------------- qbuild role ----------------
        const int s = blockIdx.x - NC;
        float* __restrict__ z = colk;
        if (threadIdx.x < ND) z[threadIdx.x] = data[(size_t)s * ND + threadIdx.x];
        *(float2*)&d2[(size_t)s * NC + threadIdx.x * 2] = make_float2(0.f, 0.f);
        __syncthreads();
        for (int p = threadIdx.x; p < KP; p += 256) {
            float val;
            if (p < NPAIR)      val = z[eop[p]] * z[dop[p]];
            else if (p < KOFF)  val = z[p - BOFF];
            else if (p == KOFF) val = 1.0f;
            else                val = 0.f;
            const unsigned short h = f2b(val);
            const unsigned short l = f2b(val - b2f(h));
            Qh[(size_t)s * KP + p] = h;
            Ql[(size_t)s * KP + p] = l;
        }
        return;
    }

    // ---------------- prep role: wave 0 only (no __syncthreads below) -------
    if (threadIdx.x >= 64) return;
    const int c = blockIdx.x;
    const int j = threadIdx.x;                        // column owned by this lane
    const unsigned colk_addr = (unsigned)(unsigned long long)(void*)colk;  // LDS byte offset

    const float inv_nc = 1.0f / n[c];
    const float* __restrict__ Sc = S + (size_t)c * ND * ND + j;

#define DECL(t) float4 A##t;
    FOR16(DECL)
#undef DECL

#define LOADT(t) {                                                   \
    const float x0 = Sc[(4*t+0)*ND] * inv_nc;                        \
    const float x1 = Sc[(4*t+1)*ND] * inv_nc;                        \
    const float x2 = Sc[(4*t+2)*ND] * inv_nc;                        \
    const float x3 = Sc[(4*t+3)*ND] * inv_nc;                        \
    A##t.x = (4*t+0 == j) ? x0 + 1e-6f : x0;                         \
    A##t.y = (4*t+1 == j) ? x1 + 1e-6f : x1;                         \
    A##t.z = (4*t+2 == j) ? x2 + 1e-6f : x2;                         \
    A##t.w = (4*t+3 == j) ? x3 + 1e-6f : x3; }
    FOR16(LOADT)
#undef LOADT

    for (int k = 0; k < ND; ++k) {
        if (j == k) {                                 // publish column k (pre-update)
#define PUB(t) *(float4*)&colk[4*t] = A##t;
            FOR16(PUB)
#undef PUB
        }
        __builtin_amdgcn_wave_barrier();
        const float rp = colk[j];                     // M[j][k] (lane-indexed LDS)
        const float p  = colk[k];                     // pivot (uniform LDS)
        float4 k4_0,k4_1,k4_2,k4_3,k4_4,k4_5,k4_6,k4_7,
               k4_8,k4_9,k4_10,k4_11,k4_12,k4_13,k4_14,k4_15;
        asm volatile(
            "ds_read_b128 %0, %16 offset:0\n\t"
            "ds_read_b128 %1, %16 offset:16\n\t"
            "ds_read_b128 %2, %16 offset:32\n\t"
            "ds_read_b128 %3, %16 offset:48\n\t"
            "ds_read_b128 %4, %16 offset:64\n\t"
            "ds_read_b128 %5, %16 offset:80\n\t"
            "ds_read_b128 %6, %16 offset:96\n\t"
            "ds_read_b128 %7, %16 offset:112\n\t"
            "ds_read_b128 %8, %16 offset:128\n\t"
            "ds_read_b128 %9, %16 offset:144\n\t"
            "ds_read_b128 %10, %16 offset:160\n\t"
            "ds_read_b128 %11, %16 offset:176\n\t"
            "ds_read_b128 %12, %16 offset:192\n\t"
            "ds_read_b128 %13, %16 offset:208\n\t"
            "ds_read_b128 %14, %16 offset:224\n\t"
            "ds_read_b128 %15, %16 offset:240\n\t"
            "s_waitcnt lgkmcnt(0)"
            : "=&v"(k4_0), "=&v"(k4_1), "=&v"(k4_2), "=&v"(k4_3),
              "=&v"(k4_4), "=&v"(k4_5), "=&v"(k4_6), "=&v"(k4_7),
              "=&v"(k4_8), "=&v"(k4_9), "=&v"(k4_10), "=&v"(k4_11),
              "=&v"(k4_12), "=&v"(k4_13), "=&v"(k4_14), "=&v"(k4_15)
            : "v"(colk_addr)
            : "memory");
        const float ip   = 1.0f / p;
        const float rowk = (j == k) ? ip : ((j < k) ? -rp : rp) * ip;  // sign identity
        const float am   = (j == k) ? 0.0f : 1.0f;    // column-k pre-zero
#define UPD(t) {                                                     \
    const float rx = A##t.x * am - k4_##t.x * rowk;                  \
    const float ry = A##t.y * am - k4_##t.y * rowk;                  \
    const float rz = A##t.z * am - k4_##t.z * rowk;                  \
    const float rw = A##t.w * am - k4_##t.w * rowk;                  \
    A##t.x = (4*t+0 == k) ? rowk : rx;                               \
    A##t.y = (4*t+1 == k) ? rowk : ry;                               \
    A##t.z = (4*t+2 == k) ? rowk : rz;                               \
    A##t.w = (4*t+3 == k) ? rowk : rw; }
        FOR16(UPD)
#undef UPD
        __builtin_amdgcn_wave_barrier();
    }

    // mirror Sinv into LDS for the pack gather; fuse y = Sinv*mu
    float y = 0.f;
#define MIR(t) {                                                     \
    *(float4*)&AcolS[j * (ND + 1) + 4*t] = A##t;                     \
    y += A##t.x * mu[c*ND + 4*t]     + A##t.y * mu[c*ND + 4*t + 1]   \
       + A##t.z * mu[c*ND + 4*t + 2] + A##t.w * mu[c*ND + 4*t + 3]; }
    FOR16(MIR)
#undef MIR
    cbuf[j] = -2.0f * y;                              // bvec values
    float kk = mu[c * ND + j] * y;
    #pragma unroll
    for (int off = 32; off > 0; off >>= 1) kk += __shfl_down(kk, off);
    const float kks = __shfl(kk, 0);
    if (j == 0) {
        int lab = 0;
        for (int q = 0; q < NK; ++q) if (clab[c * NK + q] != 0) lab = q;
        labf[c] = (float)lab;
    }
    __builtin_amdgcn_wave_barrier();

    // fused pack: beta = [sym-folded Sinv, b, k, 0pad] as bf16 hi/lo
    unsigned short* __restrict__ ph = Bph + (size_t)c * KP;
    unsigned short* __restrict__ pl = Bpl + (size_t)c * KP;
    #pragma unroll
    for (int t = 0; t < KP / 64; ++t) {               // 34 iters, p = t*64+j
        const int p = t * 64 + j;
        float val;
        if (p < NPAIR) {
            const int e = eop[p], d = dop[p];
            val = (e == d) ? AcolS[e * (ND + 1) + e]
                           : (AcolS[d * (ND + 1) + e] + AcolS[e * (ND + 1) + d]);
        } else if (p < KOFF) val = cbuf[p - BOFF];
        else if (p == KOFF)  val = kks;
        else                 val = 0.f;
        const unsigned short h = f2b(val);
        const unsigned short l = f2b(val - b2f(h));
        ph[p] = h;
        pl[p] = l;
    }
}

// ---------------- d2[s][c] = Q · Beta^T via bf16x3 MFMA, split-K x4 ----------
// R12: m97-style staging -- global_load_lds width=16, 2-barrier K-loop, NO
// VGPR round-trip (R10 staged via regs: prefetch got sunk, 65us; R11 LDS-free
// regressed to 85us). LDS 36KB unpadded (global_load_lds requires base+lane*16
// contiguity) -> 4 blocks/CU co-residency hides the barrier drain (m114).
// Unpadded 64B rows alias banks on ds_read_b128 (m97 shipped with this too);
// SQ_LDS_BANK_CONFLICT this round decides whether a swizzle is R13.
__global__ __launch_bounds__(256) void gemm_kernel(
    const unsigned short* __restrict__ Qh, const unsigned short* __restrict__ Ql,
    const unsigned short* __restrict__ Bph, const unsigned short* __restrict__ Bpl,
    float* __restrict__ d2)
{
    __shared__ unsigned short AhS[32 * 32], AlS[32 * 32];     // 2KB each
    __shared__ unsigned short BhS[256 * 32], BlS[256 * 32];   // 16KB each

    const int tid  = threadIdx.x;
    const int lane = tid & 63, w = tid >> 6;
    const int quad = lane >> 4, rlo = lane & 15;
    const int m0 = blockIdx.x * 32;      // sample tile
    const int n0 = blockIdx.y * 256;     // cluster tile
    const int koff0 = blockIdx.z * KT_PER * 32;   // this block's K-slice start

    // A staging: threads 0..127 -> Ah, 128..255 -> Al (1 seg of 16B each)
    const int arow = (tid & 127) >> 2, aseg = tid & 3;
    const unsigned short* aG = ((tid < 128) ? Qh : Ql)
                               + (size_t)(m0 + arow) * KP + aseg * 8 + koff0;
    unsigned short* aL = ((tid < 128) ? AhS : AlS) + (tid & 127) * 8;  // lane*16B

    // B staging: 4 rounds x (Bh,Bl); round rd covers rows rd*64..rd*64+63
    const int brow = tid >> 2, bseg = tid & 3;
    const unsigned short* bGh[4];
    const unsigned short* bGl[4];
    unsigned short* bLh[4];
    unsigned short* bLl[4];
    #pragma unroll
    for (int rd = 0; rd < 4; ++rd) {
        const size_t off = (size_t)(n0 + rd * 64 + brow) * KP + bseg * 8 + koff0;
        bGh[rd] = Bph + off;
        bGl[rd] = Bpl + off;
        bLh[rd] = BhS + (rd * 256 + tid) * 8;         // lane*16B contiguous
        bLl[rd] = BlS + (rd * 256 + tid) * 8;
    }

    floatx4 acc[2][4] = {};

    for (int kt = 0; kt < KT_PER; ++kt) {
        const int ko = kt * 32;
        __syncthreads();                              // frags consumed
        gl16(aG + ko, aL);
        #pragma unroll
        for (int rd = 0; rd < 4; ++rd) {
            gl16(bGh[rd] + ko, bLh[rd]);
            gl16(bGl[rd] + ko, bLl[rd]);
        }
        __syncthreads();                              // staging visible (vmcnt drain)

        short8 ah[2], al[2], bh[4], bl[4];
        #pragma unroll
        for (int i = 0; i < 2; ++i) {
            ah[i] = *(const short8*)&AhS[(i * 16 + rlo) * 32 + quad * 8];
            al[i] = *(const short8*)&AlS[(i * 16 + rlo) * 32 + quad * 8];
        }
        #pragma unroll
        for (int j2 = 0; j2 < 4; ++j2) {
            const int r = w * 64 + j2 * 16 + rlo;
            bh[j2] = *(const short8*)&BhS[r * 32 + quad * 8];
            bl[j2] = *(const short8*)&BlS[r * 32 + quad * 8];
        }
        #pragma unroll
        for (int i = 0; i < 2; ++i)
            #pragma unroll
            for (int j2 = 0; j2 < 4; ++j2) {
                acc[i][j2] = __builtin_amdgcn_mfma_f32_16x16x32_bf16(al[i], bh[j2], acc[i][j2], 0, 0, 0);
                acc[i][j2] = __builtin_amdgcn_mfma_f32_16x16x32_bf16(ah[i], bl[j2], acc[i][j2], 0, 0, 0);
                acc[i][j2] = __builtin_amdgcn_mfma_f32_16x16x32_bf16(ah[i], bh[j2], acc[i][j2], 0, 0, 0);
            }
    }

    // C layout (verified m89): col = lane&15, row = (lane>>4)*4 + reg
    #pragma unroll
    for (int i = 0; i < 2; ++i)
        #pragma unroll
        for (int j2 = 0; j2 < 4; ++j2) {
            const int m = m0 + i * 16 + quad * 4;
            const int nn = n0 + w * 64 + j2 * 16 + rlo;
            #pragma unroll
            for (int r = 0; r < 4; ++r)
                atomicAdd(&d2[(size_t)(m + r) * NC + nn], acc[i][j2][r]);
        }
}

// ---------------- scores / argmaxes: 4 waves/block, one sample per wave -----
__global__ __launch_bounds__(256) void score_kernel(
    const float* __restrict__ d2, const float* __restrict__ labf,
    float* __restrict__ out)
{
    const int s = blockIdx.x * 4 + (threadIdx.x >> 6);
    const int l = threadIdx.x & 63;

    float numer[NK];
    #pragma unroll
    for (int q = 0; q < NK; ++q) numer[q] = 0.f;
    float denom = 0.f, gmax = -1.f;
    int gidx = 0;

    #pragma unroll
    for (int i = 0; i < NC / 256; ++i) {         // float4 per lane, index-ascending
        const int c0 = i * 256 + l * 4;
        const float4 v = *(const float4*)&d2[(size_t)s * NC + c0];
        #pragma unroll
        for (int r = 0; r < 4; ++r) {
            const int c = c0 + r;
            const float G = __expf(-0.5f * ((const float*)&v)[r]);
            denom += G;
            const int lab = (int)labf[c];
            #pragma unroll
            for (int q = 0; q < NK; ++q) numer[q] += (q == lab) ? G : 0.f;
            if (G > gmax) { gmax = G; gidx = c; }   // strict > keeps first index
        }
    }

    // wave reduction (width 64); ties -> lowest cluster index (jnp first-max)
    #pragma unroll
    for (int off = 32; off > 0; off >>= 1) {
        const float og = __shfl_down(gmax, off);
        const int   oi = __shfl_down(gidx, off);
        if (og > gmax || (og == gmax && oi < gidx)) { gmax = og; gidx = oi; }
        denom += __shfl_down(denom, off);
        #pragma unroll
        for (int q = 0; q < NK; ++q) numer[q] += __shfl_down(numer[q], off);
    }

    if (l == 0) {
        const float inv = 1.0f / (denom + 1e-12f);
        float best = -1.f; int pk = 0;
        #pragma unroll
        for (int q = 0; q < NK; ++q) {
            const float sc = numer[q] * inv;
            out[(size_t)s * NK + q] = sc;
            if (sc > best) { best = sc; pk = q; }
        }
        out[(size_t)NS * NK + s]      = (float)pk;    // pred
        out[(size_t)NS * NK + NS + s] = (float)gidx;  // clusters
    }
}

extern "C" void kernel_launch(void* const* d_in, const int* in_sizes, int n_in,
                              void* d_out, int out_size, void* d_ws, size_t ws_size,
                              hipStream_t stream)
{
    const float* data = (const float*)d_in[0];
    const float* n    = (const float*)d_in[2];
    const float* mu   = (const float*)d_in[3];
    const float* S    = (const float*)d_in[4];
    const int*   clab = (const int*)d_in[5];

    char* w = (char*)d_ws;
    unsigned short* Qh  = (unsigned short*)(w);                 // 17,825,792 B
    unsigned short* Ql  = (unsigned short*)(w + 17825792);      // 17,825,792 B
    unsigned short* Bph = (unsigned short*)(w + 35651584);      //  2,228,224 B
    unsigned short* Bpl = (unsigned short*)(w + 37879808);      //  2,228,224 B
    float* d2   = (float*)(w + 40108032);                       //  8,388,608 B
    float* labf = (float*)(w + 48496640);                       //      2,048 B
    int*   eop  = (int*)  (w + 48498688);                       //      8,320 B
    int*   dop  = (int*)  (w + 48507008);                       //      8,320 B  (end 48,515,328)

    hipLaunchKernelGGL(table_kernel, dim3(1),   dim3(64),  0, stream, eop, dop);
    hipLaunchKernelGGL(prep_qbuild_kernel, dim3(NC + NS), dim3(256), 0, stream,
                       S, n, mu, clab, data, eop, dop, Bph, Bpl, Qh, Ql, d2, labf);
    hipLaunchKernelGGL(gemm_kernel,  dim3(NS / 32, NC / 256, KSPLIT), dim3(256), 0, stream,
                       Qh, Ql, Bph, Bpl, d2);
    hipLaunchKernelGGL(score_kernel, dim3(NS / 4), dim3(256), 0, stream,
                       d2, labf, (float*)d_out);
}

// Round 13
// 192.889 us; speedup vs baseline: 1.1424x; 1.0281x over previous
//
#include <hip/hip_runtime.h>
#include <hip/hip_bf16.h>
#include <math.h>

#define NS 4096      // samples
#define NC 512       // clusters
#define ND 64        // feature dim
#define NK 10        // classes
#define NPAIR 2080   // upper-triangle pairs (e<=d) of 64x64
#define KP 2176      // 2080 + 64 (linear) + 1 (const) + 31 zero-pad; 68*32
#define BOFF 2080
#define KOFF 2144
#define KSPLIT 4
#define KT_PER (KP / 32 / KSPLIT)   // 17 k-chunks per split block
#define ZB 1024                     // d2-zeroing blocks

typedef __attribute__((ext_vector_type(8))) short short8;
typedef __attribute__((ext_vector_type(4))) float floatx4;

__device__ inline unsigned short f2b(float x) {
    __hip_bfloat16 h = __float2bfloat16(x);           // RNE
    return __builtin_bit_cast(unsigned short, h);
}
__device__ inline float b2f(unsigned short u) {
    __hip_bfloat16 h = __builtin_bit_cast(__hip_bfloat16, u);
    return __bfloat162float(h);
}

// async global->LDS, 16B per lane (m97 lever); dst = wave-uniform base + lane*16
__device__ inline void gl16(const void* g, void* l) {
    __builtin_amdgcn_global_load_lds(
        (const __attribute__((address_space(1))) unsigned int*)g,
        (__attribute__((address_space(3))) unsigned int*)l, 16, 0, 0);
}

// ---------------- (e,d) table with sentinels: val[p] = z[e]*z[d] ------------
// e,d in [0,66): 64 -> sentinel 1.0, 65 -> sentinel 0.0 (zS rows carry both)
__global__ void table_kernel(int2* __restrict__ edt) {
    const int e = threadIdx.x;                        // 64 threads
    int off = e * 64 - (e * (e - 1)) / 2;             // row e starts here
    for (int d = e; d < 64; ++d) edt[off + d - e] = make_int2(e, d);
    edt[BOFF + e] = make_int2(e, 64);                 // linear terms: z*1
    if (e == 0) edt[KOFF] = make_int2(64, 64);        // const term: 1
    if (e < KP - KOFF - 1) edt[KOFF + 1 + e] = make_int2(65, 65);   // pad: 0
}

#define FOR16(M) M(0) M(1) M(2) M(3) M(4) M(5) M(6) M(7) \
                 M(8) M(9) M(10) M(11) M(12) M(13) M(14) M(15)

// ---------------- prep (Sigma^-1 + beta pack) + d2 zeroing ------------------
// Blocks [0,NC): R11-verified register GJ (named float4 + asm-batched colk
// reads). Blocks [NC, NC+ZB): zero an 8KB stripe of d2 (atomic gemm epilogue).
// Q is no longer materialized (R12: 35.6MB write + 36.8MB read was the
// dominant prep_qbuild + gemm-FETCH cost); gemm builds A-tiles on the fly.
__global__ __launch_bounds__(256, 1) void prep_kernel(
    const float* __restrict__ S, const float* __restrict__ n,
    const float* __restrict__ mu, const int* __restrict__ clab,
    const int2* __restrict__ edt, unsigned short* __restrict__ Bph,
    unsigned short* __restrict__ Bpl, float* __restrict__ d2,
    float* __restrict__ labf)
{
    __shared__ float smem[ND * (ND + 1) + 2 * ND];
    float* __restrict__ AcolS = smem;                 // [64][65] Sinv mirror
    float* __restrict__ colk  = smem + ND * (ND + 1); // column-k broadcast
    float* __restrict__ cbuf  = colk + ND;            // bvec staging

    if (blockIdx.x >= NC) {                           // ---- d2 zero role ----
        const size_t base = (size_t)(blockIdx.x - NC) * 2048 + threadIdx.x * 8;
        *(float4*)&d2[base]     = make_float4(0.f, 0.f, 0.f, 0.f);
        *(float4*)&d2[base + 4] = make_float4(0.f, 0.f, 0.f, 0.f);
        return;
    }

    if (threadIdx.x >= 64) return;                    // prep: wave 0 only
    const int c = blockIdx.x;
    const int j = threadIdx.x;                        // column owned by this lane
    const unsigned colk_addr = (unsigned)(unsigned long long)(void*)colk;

    const float inv_nc = 1.0f / n[c];
    const float* __restrict__ Sc = S + (size_t)c * ND * ND + j;

#define DECL(t) float4 A##t;
    FOR16(DECL)
#undef DECL

#define LOADT(t) {                                                   \
    const float x0 = Sc[(4*t+0)*ND] * inv_nc;                        \
    const float x1 = Sc[(4*t+1)*ND] * inv_nc;                        \
    const float x2 = Sc[(4*t+2)*ND] * inv_nc;                        \
    const float x3 = Sc[(4*t+3)*ND] * inv_nc;                        \
    A##t.x = (4*t+0 == j) ? x0 + 1e-6f : x0;                         \
    A##t.y = (4*t+1 == j) ? x1 + 1e-6f : x1;                         \
    A##t.z = (4*t+2 == j) ? x2 + 1e-6f : x2;                         \
    A##t.w = (4*t+3 == j) ? x3 + 1e-6f : x3; }
    FOR16(LOADT)
#undef LOADT

    for (int k = 0; k < ND; ++k) {
        if (j == k) {                                 // publish column k
#define PUB(t) *(float4*)&colk[4*t] = A##t;
            FOR16(PUB)
#undef PUB
        }
        __builtin_amdgcn_wave_barrier();
        const float rp = colk[j];                     // M[j][k]
        const float p  = colk[k];                     // pivot (uniform)
        float4 k4_0,k4_1,k4_2,k4_3,k4_4,k4_5,k4_6,k4_7,
               k4_8,k4_9,k4_10,k4_11,k4_12,k4_13,k4_14,k4_15;
        asm volatile(
            "ds_read_b128 %0, %16 offset:0\n\t"
            "ds_read_b128 %1, %16 offset:16\n\t"
            "ds_read_b128 %2, %16 offset:32\n\t"
            "ds_read_b128 %3, %16 offset:48\n\t"
            "ds_read_b128 %4, %16 offset:64\n\t"
            "ds_read_b128 %5, %16 offset:80\n\t"
            "ds_read_b128 %6, %16 offset:96\n\t"
            "ds_read_b128 %7, %16 offset:112\n\t"
            "ds_read_b128 %8, %16 offset:128\n\t"
            "ds_read_b128 %9, %16 offset:144\n\t"
            "ds_read_b128 %10, %16 offset:160\n\t"
            "ds_read_b128 %11, %16 offset:176\n\t"
            "ds_read_b128 %12, %16 offset:192\n\t"
            "ds_read_b128 %13, %16 offset:208\n\t"
            "ds_read_b128 %14, %16 offset:224\n\t"
            "ds_read_b128 %15, %16 offset:240\n\t"
            "s_waitcnt lgkmcnt(0)"
            : "=&v"(k4_0), "=&v"(k4_1), "=&v"(k4_2), "=&v"(k4_3),
              "=&v"(k4_4), "=&v"(k4_5), "=&v"(k4_6), "=&v"(k4_7),
              "=&v"(k4_8), "=&v"(k4_9), "=&v"(k4_10), "=&v"(k4_11),
              "=&v"(k4_12), "=&v"(k4_13), "=&v"(k4_14), "=&v"(k4_15)
            : "v"(colk_addr)
            : "memory");
        const float ip   = 1.0f / p;
        const float rowk = (j == k) ? ip : ((j < k) ? -rp : rp) * ip;  // sign identity
        const float am   = (j == k) ? 0.0f : 1.0f;
#define UPD(t) {                                                     \
    const float rx = A##t.x * am - k4_##t.x * rowk;                  \
    const float ry = A##t.y * am - k4_##t.y * rowk;                  \
    const float rz = A##t.z * am - k4_##t.z * rowk;                  \
    const float rw = A##t.w * am - k4_##t.w * rowk;                  \
    A##t.x = (4*t+0 == k) ? rowk : rx;                               \
    A##t.y = (4*t+1 == k) ? rowk : ry;                               \
    A##t.z = (4*t+2 == k) ? rowk : rz;                               \
    A##t.w = (4*t+3 == k) ? rowk : rw; }
        FOR16(UPD)
#undef UPD
        __builtin_amdgcn_wave_barrier();
    }

    float y = 0.f;
#define MIR(t) {                                                     \
    *(float4*)&AcolS[j * (ND + 1) + 4*t] = A##t;                     \
    y += A##t.x * mu[c*ND + 4*t]     + A##t.y * mu[c*ND + 4*t + 1]   \
       + A##t.z * mu[c*ND + 4*t + 2] + A##t.w * mu[c*ND + 4*t + 3]; }
    FOR16(MIR)
#undef MIR
    cbuf[j] = -2.0f * y;                              // bvec values
    float kk = mu[c * ND + j] * y;
    #pragma unroll
    for (int off = 32; off > 0; off >>= 1) kk += __shfl_down(kk, off);
    const float kks = __shfl(kk, 0);
    if (j == 0) {
        int lab = 0;
        for (int q = 0; q < NK; ++q) if (clab[c * NK + q] != 0) lab = q;
        labf[c] = (float)lab;
    }
    __builtin_amdgcn_wave_barrier();

    unsigned short* __restrict__ ph = Bph + (size_t)c * KP;
    unsigned short* __restrict__ pl = Bpl + (size_t)c * KP;
    #pragma unroll
    for (int t = 0; t < KP / 64; ++t) {               // 34 iters, p = t*64+j
        const int p = t * 64 + j;
        float val;
        if (p < NPAIR) {
            const int2 ed = edt[p];
            val = (ed.x == ed.y) ? AcolS[ed.x * (ND + 1) + ed.x]
                : (AcolS[ed.y * (ND + 1) + ed.x] + AcolS[ed.x * (ND + 1) + ed.y]);
        } else if (p < KOFF) val = cbuf[p - BOFF];
        else if (p == KOFF)  val = kks;
        else                 val = 0.f;
        const unsigned short h = f2b(val);
        const unsigned short l = f2b(val - b2f(h));
        ph[p] = h;
        pl[p] = l;
    }
}

// ---------------- d2 = Q·Beta^T, Q built on the fly; 64x256 tile, split-K x4 -
// R12 diagnosis: gemm was L2-BW-bound on redundant B staging (1024 blocks x
// 1.1MB = 1.14GB ~ 33us at L2 ceiling) and Q cost 36MB write + 36MB read.
// R13: M=64 halves B redundancy; A-tile computed in-block from the z-tile
// (identical ops to old qbuild -> bit-identical A values). A rows padded to
// 40 ushorts (stride-20 banks: conflict-free frag reads).
__global__ __launch_bounds__(256, 2) void gemm_kernel(
    const float* __restrict__ data, const int2* __restrict__ edt,
    const unsigned short* __restrict__ Bph, const unsigned short* __restrict__ Bpl,
    float* __restrict__ d2)
{
    __shared__ float zS[64 * 68];                             // z-tile + sentinels
    __shared__ unsigned short AhS[64 * 40], AlS[64 * 40];     // 5KB each
    __shared__ unsigned short BhS[256 * 32], BlS[256 * 32];   // 16KB each

    const int tid  = threadIdx.x;
    const int lane = tid & 63, w = tid >> 6;
    const int quad = lane >> 4, rlo = lane & 15;
    const int m0 = blockIdx.x * 64;      // sample tile
    const int n0 = blockIdx.y * 256;     // cluster tile
    const int koff0 = blockIdx.z * KT_PER * 32;   // this block's K-slice start

    // ---- z-tile: 64 rows x 64 floats, row stride 68 (sentinels at 64,65) ----
    #pragma unroll
    for (int q = 0; q < 4; ++q) {
        const int f = q * 256 + tid;                  // float4 id
        const int r = f >> 4, c4 = f & 15;
        const float4 v = *(const float4*)&data[(size_t)(m0 + r) * ND + c4 * 4];
        *(float4*)&zS[r * 68 + c4 * 4] = v;
    }
    if (tid < 64) { zS[tid * 68 + 64] = 1.0f; zS[tid * 68 + 65] = 0.0f; }

    // ---- B staging (R12 scheme): 8 gl16/thread per k-step ----
    const int brow = tid >> 2, bseg = tid & 3;
    const unsigned short* bGh[4];
    const unsigned short* bGl[4];
    unsigned short* bLh[4];
    unsigned short* bLl[4];
    #pragma unroll
    for (int rd = 0; rd < 4; ++rd) {
        const size_t off = (size_t)(n0 + rd * 64 + brow) * KP + bseg * 8 + koff0;
        bGh[rd] = Bph + off;
        bGl[rd] = Bpl + off;
        bLh[rd] = BhS + (rd * 256 + tid) * 8;         // lane*16B contiguous
        bLl[rd] = BlS + (rd * 256 + tid) * 8;
    }

    // ---- A on-the-fly mapping: 2 cols x 4 rows per thread ----
    const int jc = (tid & 15) * 2;                    // cols jc, jc+1
    const int rb = (tid >> 4) * 4;                    // rows rb..rb+3

    floatx4 acc[4][4] = {};
    __syncthreads();                                  // z-tile visible

    for (int kt = 0; kt < KT_PER; ++kt) {
        const int ko = kt * 32;
        if (kt) __syncthreads();                      // frags consumed
        #pragma unroll
        for (int rd = 0; rd < 4; ++rd) {
            gl16(bGh[rd] + ko, bLh[rd]);
            gl16(bGl[rd] + ko, bLl[rd]);
        }
        // A-tile compute overlaps the B-load flight
        const int2 ed0 = edt[koff0 + ko + jc];
        const int2 ed1 = edt[koff0 + ko + jc + 1];
        #pragma unroll
        for (int rr = 0; rr < 4; ++rr) {
            const int r = rb + rr;
            const float* zr = &zS[r * 68];
            const float v0 = zr[ed0.x] * zr[ed0.y];
            const float v1 = zr[ed1.x] * zr[ed1.y];
            const unsigned short h0 = f2b(v0), h1 = f2b(v1);
            const unsigned short l0 = f2b(v0 - b2f(h0)), l1 = f2b(v1 - b2f(h1));
            *(unsigned*)&AhS[r * 40 + jc] = (unsigned)h0 | ((unsigned)h1 << 16);
            *(unsigned*)&AlS[r * 40 + jc] = (unsigned)l0 | ((unsigned)l1 << 16);
        }
        __syncthreads();                              // staging + A visible

        short8 ah[4], al[4], bh[4], bl[4];
        #pragma unroll
        for (int i = 0; i < 4; ++i) {
            ah[i] = *(const short8*)&AhS[(i * 16 + rlo) * 40 + quad * 8];
            al[i] = *(const short8*)&AlS[(i * 16 + rlo) * 40 + quad * 8];
        }
        #pragma unroll
        for (int j2 = 0; j2 < 4; ++j2) {
            const int r = w * 64 + j2 * 16 + rlo;
            bh[j2] = *(const short8*)&BhS[r * 32 + quad * 8];
            bl[j2] = *(const short8*)&BlS[r * 32 + quad * 8];
        }
        #pragma unroll
        for (int i = 0; i < 4; ++i)
            #pragma unroll
            for (int j2 = 0; j2 < 4; ++j2) {
                acc[i][j2] = __builtin_amdgcn_mfma_f32_16x16x32_bf16(al[i], bh[j2], acc[i][j2], 0, 0, 0);
                acc[i][j2] = __builtin_amdgcn_mfma_f32_16x16x32_bf16(ah[i], bl[j2], acc[i][j2], 0, 0, 0);
                acc[i][j2] = __builtin_amdgcn_mfma_f32_16x16x32_bf16(ah[i], bh[j2], acc[i][j2], 0, 0, 0);
            }
    }

    // C layout (verified m89): col = lane&15, row = (lane>>4)*4 + reg
    #pragma unroll
    for (int i = 0; i < 4; ++i)
        #pragma unroll
        for (int j2 = 0; j2 < 4; ++j2) {
            const int m = m0 + i * 16 + quad * 4;
            const int nn = n0 + w * 64 + j2 * 16 + rlo;
            #pragma unroll
            for (int r = 0; r < 4; ++r)
                atomicAdd(&d2[(size_t)(m + r) * NC + nn], acc[i][j2][r]);
        }
}

// ---------------- scores / argmaxes: 4 waves/block, one sample per wave -----
__global__ __launch_bounds__(256) void score_kernel(
    const float* __restrict__ d2, const float* __restrict__ labf,
    float* __restrict__ out)
{
    const int s = blockIdx.x * 4 + (threadIdx.x >> 6);
    const int l = threadIdx.x & 63;

    float numer[NK];
    #pragma unroll
    for (int q = 0; q < NK; ++q) numer[q] = 0.f;
    float denom = 0.f, gmax = -1.f;
    int gidx = 0;

    #pragma unroll
    for (int i = 0; i < NC / 256; ++i) {         // float4 per lane, index-ascending
        const int c0 = i * 256 + l * 4;
        const float4 v = *(const float4*)&d2[(size_t)s * NC + c0];
        #pragma unroll
        for (int r = 0; r < 4; ++r) {
            const int c = c0 + r;
            const float G = __expf(-0.5f * ((const float*)&v)[r]);
            denom += G;
            const int lab = (int)labf[c];
            #pragma unroll
            for (int q = 0; q < NK; ++q) numer[q] += (q == lab) ? G : 0.f;
            if (G > gmax) { gmax = G; gidx = c; }   // strict > keeps first index
        }
    }

    #pragma unroll
    for (int off = 32; off > 0; off >>= 1) {
        const float og = __shfl_down(gmax, off);
        const int   oi = __shfl_down(gidx, off);
        if (og > gmax || (og == gmax && oi < gidx)) { gmax = og; gidx = oi; }
        denom += __shfl_down(denom, off);
        #pragma unroll
        for (int q = 0; q < NK; ++q) numer[q] += __shfl_down(numer[q], off);
    }

    if (l == 0) {
        const float inv = 1.0f / (denom + 1e-12f);
        float best = -1.f; int pk = 0;
        #pragma unroll
        for (int q = 0; q < NK; ++q) {
            const float sc = numer[q] * inv;
            out[(size_t)s * NK + q] = sc;
            if (sc > best) { best = sc; pk = q; }
        }
        out[(size_t)NS * NK + s]      = (float)pk;    // pred
        out[(size_t)NS * NK + NS + s] = (float)gidx;  // clusters
    }
}

extern "C" void kernel_launch(void* const* d_in, const int* in_sizes, int n_in,
                              void* d_out, int out_size, void* d_ws, size_t ws_size,
                              hipStream_t stream)
{
    const float* data = (const float*)d_in[0];
    const float* n    = (const float*)d_in[2];
    const float* mu   = (const float*)d_in[3];
    const float* S    = (const float*)d_in[4];
    const int*   clab = (const int*)d_in[5];

    char* w = (char*)d_ws;
    int2* edt = (int2*)(w);                                     //     17,408 B
    unsigned short* Bph = (unsigned short*)(w + 35651584);      //  2,228,224 B
    unsigned short* Bpl = (unsigned short*)(w + 37879808);      //  2,228,224 B
    float* d2   = (float*)(w + 40108032);                       //  8,388,608 B
    float* labf = (float*)(w + 48496640);                       //      2,048 B

    hipLaunchKernelGGL(table_kernel, dim3(1), dim3(64), 0, stream, edt);
    hipLaunchKernelGGL(prep_kernel,  dim3(NC + ZB), dim3(256), 0, stream,
                       S, n, mu, clab, edt, Bph, Bpl, d2, labf);
    hipLaunchKernelGGL(gemm_kernel,  dim3(NS / 64, NC / 256, KSPLIT), dim3(256), 0, stream,
                       data, edt, Bph, Bpl, d2);
    hipLaunchKernelGGL(score_kernel, dim3(NS / 4), dim3(256), 0, stream,
                       d2, labf, (float*)d_out);
}